// Round 1
// baseline (323.461 us; speedup 1.0000x reference)
//
#include <hip/hip_runtime.h>
#include <math.h>

// Problem constants
#define BB   4
#define CC   128
#define HH   64
#define WW   64
#define OUTC 128
#define LW   5
#define KK   25   // LW*LW

// ---------------------------------------------------------------------------
// Kernel 0: W2sT[c][o] = sum_{r=0..3} w2[o, c*4+r]   (transposed: c-major)
// ---------------------------------------------------------------------------
__global__ void prep_w2_kernel(const float* __restrict__ w2,
                               float* __restrict__ w2st) {
    int i = blockIdx.x * 256 + threadIdx.x;   // i < 128*128
    int c = i >> 7;
    int o = i & 127;
    const float* p = w2 + o * (4 * CC) + c * 4;
    w2st[c * OUTC + o] = p[0] + p[1] + p[2] + p[3];
}

// ---------------------------------------------------------------------------
// Kernel 1: conv1 3x3 SAME, 128->25 channels, + bias  -> k_ws[b][25][h][w]
// grid: 4(b) * 25(kc) * 4(h-tile) = 400 blocks of 256 threads
// thread: (tw = w-quad 0..15, th = row 0..15), 4 pixels each, float4 loads
// ---------------------------------------------------------------------------
__global__ void conv1_kernel(const float* __restrict__ x,
                             const float* __restrict__ w1,
                             const float* __restrict__ b1,
                             float* __restrict__ kws) {
    __shared__ float wlds[CC * 9];   // 4.6 KB: w1[kc]

    int bid = blockIdx.x;
    int ht  = bid & 3;
    int kc  = (bid >> 2) % KK;
    int b   = bid / (4 * KK);

    int t  = threadIdx.x;
    // stage w1[kc] into LDS
    for (int idx = t; idx < CC * 9; idx += 256)
        wlds[idx] = w1[kc * (CC * 9) + idx];
    __syncthreads();

    int tw = t & 15;         // w-quad
    int th = t >> 4;         // row in tile
    int w0 = tw * 4;
    int h  = ht * 16 + th;

    float bias = b1[kc];
    float acc0 = bias, acc1 = bias, acc2 = bias, acc3 = bias;

    const float* xb = x + (size_t)(b * CC) * (HH * WW);
    for (int c = 0; c < CC; ++c) {
        const float* wrow = &wlds[c * 9];
        const float* xc   = xb + c * (HH * WW);
        #pragma unroll
        for (int dy = 0; dy < 3; ++dy) {
            int y = h + dy - 1;
            if (y < 0 || y >= HH) continue;
            const float* row = xc + y * WW;
            float4 v = *(const float4*)(row + w0);
            float left  = (w0 > 0)      ? row[w0 - 1] : 0.f;
            float right = (w0 + 4 < WW) ? row[w0 + 4] : 0.f;
            float wa = wrow[dy * 3 + 0];
            float wb = wrow[dy * 3 + 1];
            float wc = wrow[dy * 3 + 2];
            acc0 += left * wa + v.x * wb + v.y * wc;
            acc1 += v.x  * wa + v.y * wb + v.z * wc;
            acc2 += v.y  * wa + v.z * wb + v.w * wc;
            acc3 += v.z  * wa + v.w * wb + right * wc;
        }
    }

    float4 r = make_float4(acc0, acc1, acc2, acc3);
    *(float4*)(kws + ((size_t)(b * KK + kc) * HH + h) * WW + w0) = r;
}

// ---------------------------------------------------------------------------
// Kernel 2: fused softmax + local attention + (C->OUT) GEMM + 2x2-replicated
//           output write.
// grid: 4(b) * 64(h) * 2(w-half) = 512 blocks of 256 threads
// each block handles 32 pixels (w = wh*32 .. wh*32+31)
// ---------------------------------------------------------------------------
__global__ void fused_kernel(const float* __restrict__ x,
                             const float* __restrict__ w2st,
                             const float* __restrict__ b2,
                             const float* __restrict__ kws,
                             float* __restrict__ out) {
    __shared__ float pk[KK][32];      // softmax probs per pixel   (3.2 KB)
    __shared__ float sK[CC][32];      // attention output s[c][w]  (16 KB)
    __shared__ float wch[16][OUTC];   // W2sT chunk                (8 KB)

    int bid = blockIdx.x;
    int wh  = bid & 1;
    int h   = (bid >> 1) & 63;
    int b   = bid >> 7;

    int t = threadIdx.x;
    int w = t & 31;           // pixel within the 32-wide strip
    int g = t >> 5;           // group 0..7

    // ---- Phase 1: load conv1 output + softmax over 25 channels ----
    for (int idx = t; idx < KK * 32; idx += 256) {
        int kk = idx >> 5;
        int ww = idx & 31;
        pk[kk][ww] = kws[((size_t)(b * KK + kk) * HH + h) * WW + wh * 32 + ww];
    }
    __syncthreads();

    if (t < 32) {
        float m = -1e30f;
        for (int k = 0; k < KK; ++k) m = fmaxf(m, pk[k][t]);
        float s = 0.f;
        for (int k = 0; k < KK; ++k) {
            float e = __expf(pk[k][t] - m);
            pk[k][t] = e;
            s += e;
        }
        float inv = 1.f / s;
        for (int k = 0; k < KK; ++k) pk[k][t] *= inv;
    }
    __syncthreads();

    // ---- Phase 2: s[c][w] = sum_k p[k] * x[b,c,h+di-2, xw+dj-2] ----
    int xw = wh * 32 + w;
    const float* xb = x + (size_t)(b * CC) * (HH * WW);
    for (int ci = 0; ci < 16; ++ci) {
        int c = ci * 8 + g;
        const float* xc = xb + c * (HH * WW);
        float acc = 0.f;
        #pragma unroll
        for (int di = 0; di < LW; ++di) {
            int y = h + di - 2;
            if (y < 0 || y >= HH) continue;
            const float* row = xc + y * WW;
            #pragma unroll
            for (int dj = 0; dj < LW; ++dj) {
                int xx = xw + dj - 2;
                if (xx < 0 || xx >= WW) continue;
                acc += pk[di * LW + dj][w] * row[xx];
            }
        }
        sK[c][w] = acc;
    }
    __syncthreads();

    // ---- Phase 3: V[o] = b2[o] + sum_c s[c] * W2sT[c][o]; write 2x2 ----
    float acc[16];
    #pragma unroll
    for (int oi = 0; oi < 16; ++oi) acc[oi] = b2[oi * 8 + g];

    for (int cc = 0; cc < 8; ++cc) {
        __syncthreads();   // protect wch from previous chunk's readers
        for (int idx = t; idx < 16 * OUTC; idx += 256) {
            int cl = idx >> 7;
            int o  = idx & 127;
            wch[cl][o] = w2st[(size_t)(cc * 16 + cl) * OUTC + o];
        }
        __syncthreads();
        #pragma unroll 4
        for (int cl = 0; cl < 16; ++cl) {
            float sv = sK[cc * 16 + cl][w];
            #pragma unroll
            for (int oi = 0; oi < 16; ++oi)
                acc[oi] += sv * wch[cl][oi * 8 + g];
        }
    }

    // write: out[b, o, 2h+dr, 2*(wh*32+w)+dc] for dr,dc in {0,1}
    int y0 = 2 * h;
    int xcol = 2 * (wh * 32 + w);
    #pragma unroll
    for (int oi = 0; oi < 16; ++oi) {
        int o = oi * 8 + g;
        float v = acc[oi];
        float2 v2 = make_float2(v, v);
        float* base = out + ((size_t)(b * OUTC + o) * (2 * HH) + y0) * (2 * WW) + xcol;
        *(float2*)(base)            = v2;   // row 2h
        *(float2*)(base + 2 * WW)   = v2;   // row 2h+1
    }
}

// ---------------------------------------------------------------------------
extern "C" void kernel_launch(void* const* d_in, const int* in_sizes, int n_in,
                              void* d_out, int out_size, void* d_ws, size_t ws_size,
                              hipStream_t stream) {
    const float* x  = (const float*)d_in[0];
    const float* w1 = (const float*)d_in[1];
    const float* b1 = (const float*)d_in[2];
    const float* w2 = (const float*)d_in[3];
    const float* b2 = (const float*)d_in[4];
    float* out = (float*)d_out;

    float* kws  = (float*)d_ws;                 // 4*25*64*64 = 409600 floats
    float* w2st = kws + (size_t)BB * KK * HH * WW;  // 128*128 floats

    prep_w2_kernel<<<64, 256, 0, stream>>>(w2, w2st);
    conv1_kernel<<<BB * KK * 4, 256, 0, stream>>>(x, w1, b1, kws);
    fused_kernel<<<BB * HH * 2, 256, 0, stream>>>(x, w2st, b2, kws, out);
}

// Round 2
// 247.053 us; speedup vs baseline: 1.3093x; 1.3093x over previous
//
#include <hip/hip_runtime.h>
#include <math.h>

// Problem constants
#define BB   4
#define CC   128
#define HH   64
#define WW   64
#define OUTC 128
#define LW   5
#define KK   25   // LW*LW
#define CHALF 64  // c-split half size

// ---------------------------------------------------------------------------
// Kernel 0: W2sT[c][o] = sum_{r=0..3} w2[o, c*4+r]   (transposed: c-major)
// ---------------------------------------------------------------------------
__global__ void prep_w2_kernel(const float* __restrict__ w2,
                               float* __restrict__ w2st) {
    int i = blockIdx.x * 256 + threadIdx.x;   // i < 128*128
    int c = i >> 7;
    int o = i & 127;
    const float* p = w2 + o * (4 * CC) + c * 4;
    w2st[c * OUTC + o] = p[0] + p[1] + p[2] + p[3];
}

// ---------------------------------------------------------------------------
// Kernel 1: conv1 3x3 SAME, partial over a 64-channel half, NO bias.
// grid: 4(b) * 25(kc) * 4(h-tile) * 2(c-half) = 800 blocks of 256 threads
// thread: (tw = w-quad 0..15, th = row 0..15), 4 pixels each, float4 loads
// output: kws[ch][b][kc][h][w]  (two bias-less partials)
// ---------------------------------------------------------------------------
__global__ void conv1_kernel(const float* __restrict__ x,
                             const float* __restrict__ w1,
                             float* __restrict__ kws) {
    __shared__ float wlds[CHALF * 12];   // 3 KB: w1[kc, chalf], padded 9->12

    int bid = blockIdx.x;
    int ch  = bid & 1;
    int ht  = (bid >> 1) & 3;
    int kc  = (bid >> 3) % KK;
    int b   = bid / (8 * KK);

    int t = threadIdx.x;
    // stage this block's weights into LDS, padded to 12 floats per c
    for (int i = t; i < CHALF * 9; i += 256) {
        int c = i / 9;
        int j = i - c * 9;
        wlds[c * 12 + j] = w1[(size_t)kc * (CC * 9) + (ch * CHALF + c) * 9 + j];
    }
    __syncthreads();

    int tw = t & 15;         // w-quad
    int th = t >> 4;         // row in tile
    int w0 = tw * 4;
    int h  = ht * 16 + th;

    // branch-free row handling: clamped rows + weight masks
    float m0 = (h - 1 >= 0) ? 1.f : 0.f;
    float m2 = (h + 1 < HH) ? 1.f : 0.f;
    int y0 = (h - 1 >= 0) ? (h - 1) : 0;
    int y2 = (h + 1 < HH) ? (h + 1) : (HH - 1);
    bool has_l = (w0 > 0);
    bool has_r = (w0 + 4 < WW);

    float acc0 = 0.f, acc1 = 0.f, acc2 = 0.f, acc3 = 0.f;

    const float* xb = x + ((size_t)b * CC + ch * CHALF) * (HH * WW);

    #pragma unroll 2
    for (int c = 0; c < CHALF; ++c) {
        const float* xc = xb + c * (HH * WW);
        const float* r0 = xc + y0 * WW;
        const float* r1 = xc + h  * WW;
        const float* r2 = xc + y2 * WW;

        // loads first (pipeline-friendly)
        float4 v0 = *(const float4*)(r0 + w0);
        float4 v1 = *(const float4*)(r1 + w0);
        float4 v2 = *(const float4*)(r2 + w0);
        float l0 = has_l ? r0[w0 - 1] : 0.f;
        float l1 = has_l ? r1[w0 - 1] : 0.f;
        float l2 = has_l ? r2[w0 - 1] : 0.f;
        float q0 = has_r ? r0[w0 + 4] : 0.f;
        float q1 = has_r ? r1[w0 + 4] : 0.f;
        float q2 = has_r ? r2[w0 + 4] : 0.f;

        const float* w9 = &wlds[c * 12];
        float4 f0 = *(const float4*)(w9);
        float4 f1 = *(const float4*)(w9 + 4);
        float4 f2 = *(const float4*)(w9 + 8);
        float w00 = f0.x * m0, w01 = f0.y * m0, w02 = f0.z * m0;
        float w10 = f0.w,      w11 = f1.x,      w12 = f1.y;
        float w20 = f1.z * m2, w21 = f1.w * m2, w22 = f2.x * m2;

        acc0 += l0   * w00 + v0.x * w01 + v0.y * w02;
        acc1 += v0.x * w00 + v0.y * w01 + v0.z * w02;
        acc2 += v0.y * w00 + v0.z * w01 + v0.w * w02;
        acc3 += v0.z * w00 + v0.w * w01 + q0   * w02;

        acc0 += l1   * w10 + v1.x * w11 + v1.y * w12;
        acc1 += v1.x * w10 + v1.y * w11 + v1.z * w12;
        acc2 += v1.y * w10 + v1.z * w11 + v1.w * w12;
        acc3 += v1.z * w10 + v1.w * w11 + q1   * w12;

        acc0 += l2   * w20 + v2.x * w21 + v2.y * w22;
        acc1 += v2.x * w20 + v2.y * w21 + v2.z * w22;
        acc2 += v2.y * w20 + v2.z * w21 + v2.w * w22;
        acc3 += v2.z * w20 + v2.w * w21 + q2   * w22;
    }

    float4 r = make_float4(acc0, acc1, acc2, acc3);
    size_t outoff = ((size_t)ch * BB * KK + (size_t)(b * KK + kc)) * (HH * WW)
                    + (size_t)h * WW + w0;
    *(float4*)(kws + outoff) = r;
}

// ---------------------------------------------------------------------------
// Kernel 2: fused softmax + local attention + (C->OUT) GEMM + 2x2-replicated
//           output write.
// grid: 4(b) * 64(h) * 2(w-half) = 512 blocks of 256 threads
// ---------------------------------------------------------------------------
__global__ void fused_kernel(const float* __restrict__ x,
                             const float* __restrict__ w2st,
                             const float* __restrict__ b1,
                             const float* __restrict__ b2,
                             const float* __restrict__ kws,
                             float* __restrict__ out) {
    __shared__ float pk[KK][32];        // softmax probs per pixel   (3.2 KB)
    __shared__ float sK[CC][32];        // attention output s[c][w]  (16 KB)
    __shared__ float wch[16][8][20];    // W2sT chunk [cl][g][oi+pad] (10.2 KB)

    int bid = blockIdx.x;
    int wh  = bid & 1;
    int h   = (bid >> 1) & 63;
    int b   = bid >> 7;

    int t = threadIdx.x;
    int w = t & 31;           // pixel within the 32-wide strip
    int g = t >> 5;           // group 0..7

    // ---- Phase 1: sum conv1 partials + bias, softmax over 25 channels ----
    const size_t chstride = (size_t)BB * KK * HH * WW;
    for (int idx = t; idx < KK * 32; idx += 256) {
        int kk = idx >> 5;
        int ww = idx & 31;
        size_t o = ((size_t)(b * KK + kk) * HH + h) * WW + wh * 32 + ww;
        pk[kk][ww] = kws[o] + kws[o + chstride] + b1[kk];
    }
    __syncthreads();

    if (t < 32) {
        float m = -1e30f;
        for (int k = 0; k < KK; ++k) m = fmaxf(m, pk[k][t]);
        float s = 0.f;
        for (int k = 0; k < KK; ++k) {
            float e = __expf(pk[k][t] - m);
            pk[k][t] = e;
            s += e;
        }
        float inv = 1.f / s;
        for (int k = 0; k < KK; ++k) pk[k][t] *= inv;
    }
    __syncthreads();

    // ---- Phase 2: s[c][w] = sum_k p[k] * x[b,c,h+di-2, xw+dj-2] ----
    // hoist bounds out of the c-loop: masked probs + clamped offsets
    int xw = wh * 32 + w;
    float pw[KK];
    int   off[KK];
    #pragma unroll
    for (int di = 0; di < LW; ++di) {
        int y = h + di - 2;
        bool yok = (y >= 0) && (y < HH);
        int yc = yok ? y : (y < 0 ? 0 : HH - 1);
        #pragma unroll
        for (int dj = 0; dj < LW; ++dj) {
            int xx = xw + dj - 2;
            bool xok = (xx >= 0) && (xx < WW);
            int xc_ = xok ? xx : (xx < 0 ? 0 : WW - 1);
            int tap = di * LW + dj;
            pw[tap]  = (yok && xok) ? pk[tap][w] : 0.f;
            off[tap] = yc * WW + xc_;
        }
    }

    const float* xb = x + (size_t)(b * CC) * (HH * WW);
    for (int ci = 0; ci < 16; ++ci) {
        int c = ci * 8 + g;
        const float* xc = xb + c * (HH * WW);
        float acc = 0.f;
        #pragma unroll
        for (int tap = 0; tap < KK; ++tap)
            acc += pw[tap] * xc[off[tap]];
        sK[c][w] = acc;
    }
    __syncthreads();

    // ---- Phase 3: V[o] = b2[o] + sum_c s[c] * W2sT[c][o]; write 2x2 ----
    float acc[16];
    #pragma unroll
    for (int oi = 0; oi < 16; ++oi) acc[oi] = b2[oi * 8 + g];

    for (int cc = 0; cc < 8; ++cc) {
        __syncthreads();   // protect wch from previous chunk's readers
        for (int idx = t; idx < 16 * OUTC; idx += 256) {
            int cl = idx >> 7;
            int o  = idx & 127;
            wch[cl][o & 7][o >> 3] = w2st[(size_t)(cc * 16 + cl) * OUTC + o];
        }
        __syncthreads();
        #pragma unroll 4
        for (int cl = 0; cl < 16; ++cl) {
            float sv = sK[cc * 16 + cl][w];
            float4 wa = *(const float4*)&wch[cl][g][0];
            float4 wb = *(const float4*)&wch[cl][g][4];
            float4 wc = *(const float4*)&wch[cl][g][8];
            float4 wd = *(const float4*)&wch[cl][g][12];
            acc[0]  += sv * wa.x;  acc[1]  += sv * wa.y;
            acc[2]  += sv * wa.z;  acc[3]  += sv * wa.w;
            acc[4]  += sv * wb.x;  acc[5]  += sv * wb.y;
            acc[6]  += sv * wb.z;  acc[7]  += sv * wb.w;
            acc[8]  += sv * wc.x;  acc[9]  += sv * wc.y;
            acc[10] += sv * wc.z;  acc[11] += sv * wc.w;
            acc[12] += sv * wd.x;  acc[13] += sv * wd.y;
            acc[14] += sv * wd.z;  acc[15] += sv * wd.w;
        }
    }

    // write: out[b, o, 2h+dr, 2*(wh*32+w)+dc] for dr,dc in {0,1}
    int y0 = 2 * h;
    int xcol = 2 * (wh * 32 + w);
    #pragma unroll
    for (int oi = 0; oi < 16; ++oi) {
        int o = oi * 8 + g;
        float v = acc[oi];
        float2 v2 = make_float2(v, v);
        float* base = out + ((size_t)(b * OUTC + o) * (2 * HH) + y0) * (2 * WW) + xcol;
        *(float2*)(base)          = v2;   // row 2h
        *(float2*)(base + 2 * WW) = v2;   // row 2h+1
    }
}

// ---------------------------------------------------------------------------
extern "C" void kernel_launch(void* const* d_in, const int* in_sizes, int n_in,
                              void* d_out, int out_size, void* d_ws, size_t ws_size,
                              hipStream_t stream) {
    const float* x  = (const float*)d_in[0];
    const float* w1 = (const float*)d_in[1];
    const float* b1 = (const float*)d_in[2];
    const float* w2 = (const float*)d_in[3];
    const float* b2 = (const float*)d_in[4];
    float* out = (float*)d_out;

    float* kws  = (float*)d_ws;                          // 2 * 409600 floats
    float* w2st = kws + 2 * (size_t)BB * KK * HH * WW;   // 128*128 floats

    prep_w2_kernel<<<64, 256, 0, stream>>>(w2, w2st);
    conv1_kernel<<<BB * KK * 8, 256, 0, stream>>>(x, w1, kws);
    fused_kernel<<<BB * HH * 2, 256, 0, stream>>>(x, w2st, b1, b2, kws, out);
}

// Round 3
// 190.905 us; speedup vs baseline: 1.6944x; 1.2941x over previous
//
#include <hip/hip_runtime.h>
#include <math.h>

// Problem constants
#define BB   4
#define CC   128
#define HH   64
#define WW   64
#define OUTC 128
#define LW   5
#define KK   25   // LW*LW

// ---------------------------------------------------------------------------
// Kernel 0: W2sT[c][o] = sum_{r=0..3} w2[o, c*4+r]   (transposed: c-major)
// ---------------------------------------------------------------------------
__global__ void prep_w2_kernel(const float* __restrict__ w2,
                               float* __restrict__ w2st) {
    int i = blockIdx.x * 256 + threadIdx.x;   // i < 128*128
    int c = i >> 7;
    int o = i & 127;
    const float* p = w2 + o * (4 * CC) + c * 4;
    w2st[c * OUTC + o] = p[0] + p[1] + p[2] + p[3];
}

// ---------------------------------------------------------------------------
// Kernel 1: conv1 3x3 SAME — ALL 25 kc per block, 16-channel chunk,
//           atomicAdd partials into zeroed kws (no bias; fused adds b1).
// grid: 4(b) * 16(h-tile of 4 rows) * 8(c-chunk) = 512 blocks, 256 threads.
// thread: 1 pixel (w = t&63, row = t>>6). Weights via wave-uniform indices
// -> s_load; v_fmac with SGPR operand. 225 FMA per 9 coalesced x loads.
// ---------------------------------------------------------------------------
__global__ void conv1_kernel(const float* __restrict__ x,
                             const float* __restrict__ w1,
                             float* __restrict__ kws) {
    int bid = blockIdx.x;
    int cch = bid & 7;
    int ht  = (bid >> 3) & 15;
    int b   = bid >> 7;

    int t = threadIdx.x;
    int w = t & 63;
    int h = ht * 4 + (t >> 6);

    // boundary masks (fold zero-padding into x values)
    float mt = (h > 0)      ? 1.f : 0.f;
    float mb = (h < HH - 1) ? 1.f : 0.f;
    float ml = (w > 0)      ? 1.f : 0.f;
    float mr = (w < WW - 1) ? 1.f : 0.f;
    float m[9] = { mt*ml, mt, mt*mr,  ml, 1.f, mr,  mb*ml, mb, mb*mr };

    int yo0 = ((h > 0) ? h - 1 : 0) * WW;
    int yo1 = h * WW;
    int yo2 = ((h < HH - 1) ? h + 1 : HH - 1) * WW;
    int c0 = (w > 0) ? w - 1 : 0;
    int c1 = w;
    int c2 = (w < WW - 1) ? w + 1 : WW - 1;

    float acc[KK];
    #pragma unroll
    for (int k = 0; k < KK; ++k) acc[k] = 0.f;

    const float* xb = x + ((size_t)b * CC + cch * 16) * (HH * WW);
    for (int cc = 0; cc < 16; ++cc) {
        const float* xc = xb + cc * (HH * WW);
        float xv[9];
        xv[0] = xc[yo0 + c0]; xv[1] = xc[yo0 + c1]; xv[2] = xc[yo0 + c2];
        xv[3] = xc[yo1 + c0]; xv[4] = xc[yo1 + c1]; xv[5] = xc[yo1 + c2];
        xv[6] = xc[yo2 + c0]; xv[7] = xc[yo2 + c1]; xv[8] = xc[yo2 + c2];
        #pragma unroll
        for (int j = 0; j < 9; ++j) xv[j] *= m[j];

        const float* wp = w1 + (size_t)(cch * 16 + cc) * 9;  // uniform base
        #pragma unroll
        for (int kc = 0; kc < KK; ++kc) {
            #pragma unroll
            for (int j = 0; j < 9; ++j)
                acc[kc] += wp[(size_t)kc * (CC * 9) + j] * xv[j];
        }
    }

    float* kb = kws + (size_t)b * KK * (HH * WW) + h * WW + w;
    #pragma unroll
    for (int kc = 0; kc < KK; ++kc)
        atomicAdd(kb + (size_t)kc * (HH * WW), acc[kc]);
}

// ---------------------------------------------------------------------------
// Kernel 2: fused softmax + local attention + (C->OUT) GEMM + 2x2-replicated
//           output write.
// grid: 4(b) * 64(h) * 2(w-half) = 512 blocks of 256 threads
// ---------------------------------------------------------------------------
__global__ __launch_bounds__(256) void fused_kernel(
        const float* __restrict__ x,
        const float* __restrict__ w2st,
        const float* __restrict__ b1,
        const float* __restrict__ b2,
        const float* __restrict__ kws,
        float* __restrict__ out) {
    __shared__ float pk[KK * 32];        // softmax probs            (3.2 KB)
    __shared__ float xld[16 * 5 * 40];   // x tile, zero halo        (12.8 KB)
    __shared__ float sK[CC * 32];        // attention output s[c][w] (16 KB)
    __shared__ float wch[32 * OUTC];     // W2sT chunk [cc][o]       (16 KB)

    int bid = blockIdx.x;
    int wh  = bid & 1;
    int h   = (bid >> 1) & 63;
    int b   = bid >> 7;
    int t   = threadIdx.x;

    // ---- Phase 1: load conv1 logits + bias, softmax over 25 channels ----
    for (int i = t; i < KK * 32; i += 256) {
        int kk = i >> 5, ww = i & 31;
        pk[kk * 32 + ww] =
            kws[(size_t)(b * KK + kk) * (HH * WW) + h * WW + wh * 32 + ww]
            + b1[kk];
    }
    __syncthreads();

    if (t < 32) {
        float mx = -1e30f;
        for (int k = 0; k < KK; ++k) mx = fmaxf(mx, pk[k * 32 + t]);
        float s = 0.f;
        for (int k = 0; k < KK; ++k) {
            float e = __expf(pk[k * 32 + t] - mx);
            pk[k * 32 + t] = e;
            s += e;
        }
        float inv = 1.f / s;
        for (int k = 0; k < KK; ++k) pk[k * 32 + t] *= inv;
    }
    __syncthreads();

    // ---- Phase 2: s[c][w] = sum_k p[k][w] * xpad[c][h+di-2][w+dj-2] ----
    // thread = (clane = t>>4 in 0..15, pp = t&15 -> pixels {2pp, 2pp+1})
    int pp = t & 15, clane = t >> 4;
    float p0[KK], p1[KK];
    #pragma unroll
    for (int k = 0; k < KK; ++k) {
        p0[k] = pk[k * 32 + 2 * pp];
        p1[k] = pk[k * 32 + 2 * pp + 1];
    }

    const float* xb = x + (size_t)(b * CC) * (HH * WW);
    for (int ch = 0; ch < 8; ++ch) {
        __syncthreads();   // previous chunk's readers done
        for (int i = t; i < 16 * 200; i += 256) {
            int cc  = i / 200;
            int rem = i - cc * 200;
            int di  = rem / 40;
            int w40 = rem - di * 40;
            int y    = h + di - 2;
            int xcol = wh * 32 + w40 - 2;
            float v = 0.f;
            if (y >= 0 && y < HH && xcol >= 0 && xcol < WW)
                v = xb[(size_t)(ch * 16 + cc) * (HH * WW) + y * WW + xcol];
            xld[cc * 200 + di * 40 + w40] = v;
        }
        __syncthreads();

        float a0 = 0.f, a1 = 0.f;
        const float* xr = &xld[clane * 200];
        #pragma unroll
        for (int di = 0; di < 5; ++di) {
            float xv[6];
            #pragma unroll
            for (int j = 0; j < 6; ++j) xv[j] = xr[di * 40 + 2 * pp + j];
            #pragma unroll
            for (int dj = 0; dj < 5; ++dj) {
                a0 += p0[di * 5 + dj] * xv[dj];
                a1 += p1[di * 5 + dj] * xv[dj + 1];
            }
        }
        int c = ch * 16 + clane;
        sK[c * 32 + 2 * pp]     = a0;
        sK[c * 32 + 2 * pp + 1] = a1;
    }

    // ---- Phase 3: V[o][px] = b2[o] + sum_c s[c][px] * W2sT[c][o] ----
    // thread = (slot = t&7 -> 4 px, og = t>>3 -> 4 outputs)
    int slot = t & 7, og = t >> 3;
    float4 bv = *(const float4*)(b2 + og * 4);
    float acc[16];  // acc[oi*4 + p]
    acc[0] = bv.x; acc[1] = bv.x; acc[2]  = bv.x; acc[3]  = bv.x;
    acc[4] = bv.y; acc[5] = bv.y; acc[6]  = bv.y; acc[7]  = bv.y;
    acc[8] = bv.z; acc[9] = bv.z; acc[10] = bv.z; acc[11] = bv.z;
    acc[12] = bv.w; acc[13] = bv.w; acc[14] = bv.w; acc[15] = bv.w;

    for (int ch = 0; ch < 4; ++ch) {
        __syncthreads();
        for (int i = t; i < 32 * OUTC; i += 256)
            wch[i] = w2st[ch * 32 * OUTC + i];
        __syncthreads();
        #pragma unroll 4
        for (int cc = 0; cc < 32; ++cc) {
            int c = ch * 32 + cc;
            float4 s4 = *(const float4*)&sK[c * 32 + slot * 4];
            float4 w4 = *(const float4*)&wch[cc * OUTC + og * 4];
            acc[0]  += w4.x * s4.x; acc[1]  += w4.x * s4.y;
            acc[2]  += w4.x * s4.z; acc[3]  += w4.x * s4.w;
            acc[4]  += w4.y * s4.x; acc[5]  += w4.y * s4.y;
            acc[6]  += w4.y * s4.z; acc[7]  += w4.y * s4.w;
            acc[8]  += w4.z * s4.x; acc[9]  += w4.z * s4.y;
            acc[10] += w4.z * s4.z; acc[11] += w4.z * s4.w;
            acc[12] += w4.w * s4.x; acc[13] += w4.w * s4.y;
            acc[14] += w4.w * s4.z; acc[15] += w4.w * s4.w;
        }
    }

    // ---- write: 2x2-replicated, float4 pairs ----
    float* ob = out + (size_t)(b * OUTC) * (4 * HH * WW);
    int y0   = 2 * h;
    int colb = 2 * (wh * 32 + slot * 4);
    #pragma unroll
    for (int oi = 0; oi < 4; ++oi) {
        int o = og * 4 + oi;
        float4 lo = make_float4(acc[oi*4+0], acc[oi*4+0], acc[oi*4+1], acc[oi*4+1]);
        float4 hi = make_float4(acc[oi*4+2], acc[oi*4+2], acc[oi*4+3], acc[oi*4+3]);
        float* r0 = ob + ((size_t)o * (2 * HH) + y0) * (2 * WW) + colb;
        *(float4*)(r0)              = lo;
        *(float4*)(r0 + 4)          = hi;
        *(float4*)(r0 + 2 * WW)     = lo;
        *(float4*)(r0 + 2 * WW + 4) = hi;
    }
}

// ---------------------------------------------------------------------------
extern "C" void kernel_launch(void* const* d_in, const int* in_sizes, int n_in,
                              void* d_out, int out_size, void* d_ws, size_t ws_size,
                              hipStream_t stream) {
    const float* x  = (const float*)d_in[0];
    const float* w1 = (const float*)d_in[1];
    const float* b1 = (const float*)d_in[2];
    const float* w2 = (const float*)d_in[3];
    const float* b2 = (const float*)d_in[4];
    float* out = (float*)d_out;

    float* kws  = (float*)d_ws;                      // 4*25*64*64 floats
    float* w2st = kws + (size_t)BB * KK * HH * WW;   // 128*128 floats

    // zero the atomic accumulation buffer (ws is re-poisoned every launch)
    hipMemsetAsync(kws, 0, (size_t)BB * KK * HH * WW * sizeof(float), stream);

    prep_w2_kernel<<<64, 256, 0, stream>>>(w2, w2st);
    conv1_kernel<<<BB * 16 * 8, 256, 0, stream>>>(x, w1, kws);
    fused_kernel<<<BB * HH * 2, 256, 0, stream>>>(x, w2st, b1, b2, kws, out);
}

// Round 4
// 153.535 us; speedup vs baseline: 2.1068x; 1.2434x over previous
//
#include <hip/hip_runtime.h>
#include <math.h>

// Problem constants
#define BB   4
#define CC   128
#define HH   64
#define WW   64
#define OUTC 128
#define LW   5
#define KK   25   // LW*LW

// ---------------------------------------------------------------------------
// Kernel 0: W2sT[c][o] = sum_{r=0..3} w2[o, c*4+r]   (transposed: c-major)
// ---------------------------------------------------------------------------
__global__ void prep_w2_kernel(const float* __restrict__ w2,
                               float* __restrict__ w2st) {
    int i = blockIdx.x * 256 + threadIdx.x;   // i < 128*128
    int c = i >> 7;
    int o = i & 127;
    const float* p = w2 + o * (4 * CC) + c * 4;
    w2st[c * OUTC + o] = p[0] + p[1] + p[2] + p[3];
}

// ---------------------------------------------------------------------------
// Kernel 1: conv1 3x3 SAME. Block = (b, 4-row tile, c-split cs, kc-group of 5).
// grid: 4 * 16 * ncs * 5 blocks of 256 threads (ncs=4 -> 1280 blocks).
// x staged in LDS (4 channels x 6 rows x 64, zero vertical halo); weights via
// wave-uniform s_load (45 dwords/c); 45 FMA per 9 LDS reads.
// Output: per-cs partial slabs kwsP[cs][b][kc][h][w], plain stores.
// ---------------------------------------------------------------------------
__global__ __launch_bounds__(256) void conv1_kernel(
        const float* __restrict__ x,
        const float* __restrict__ w1,
        float* __restrict__ kwsP,
        int ncs, int cper) {
    __shared__ float xt[6 * 4 * 64];   // [r][ci][col], 6 KB

    int bid = blockIdx.x;
    int kcg  = bid % 5;
    int rest = bid / 5;
    int cs   = rest % ncs;
    rest /= ncs;
    int ht = rest & 15;
    int b  = rest >> 4;

    int t  = threadIdx.x;
    int w  = t & 63;
    int th = t >> 6;
    int h  = ht * 4 + th;

    float ml = (w > 0)  ? 1.f : 0.f;
    float mr = (w < 63) ? 1.f : 0.f;
    int wl = (w > 0)  ? w - 1 : 0;
    int wr = (w < 63) ? w + 1 : 63;

    float acc[5] = {0.f, 0.f, 0.f, 0.f, 0.f};

    const float* xb = x + ((size_t)b * CC + cs * cper) * (HH * WW);
    const float* wb = w1 + (size_t)(kcg * 5) * (CC * 9) + (size_t)(cs * cper) * 9;

    for (int c0 = 0; c0 < cper; c0 += 4) {
        __syncthreads();   // previous iteration's readers done
        // stage 4 channels x 6 rows (vertical halo zero-filled)
        for (int i = t; i < 1536; i += 256) {
            int r   = i >> 8;
            int ci  = (i >> 6) & 3;
            int col = i & 63;
            int y = ht * 4 - 1 + r;
            float v = 0.f;
            if (y >= 0 && y < HH)
                v = xb[(size_t)(c0 + ci) * (HH * WW) + y * WW + col];
            xt[i] = v;
        }
        __syncthreads();

        #pragma unroll
        for (int ci = 0; ci < 4; ++ci) {
            const float* xr = &xt[ci * 64];
            float xv0 = xr[(th + 0) * 256 + wl] * ml;
            float xv1 = xr[(th + 0) * 256 + w];
            float xv2 = xr[(th + 0) * 256 + wr] * mr;
            float xv3 = xr[(th + 1) * 256 + wl] * ml;
            float xv4 = xr[(th + 1) * 256 + w];
            float xv5 = xr[(th + 1) * 256 + wr] * mr;
            float xv6 = xr[(th + 2) * 256 + wl] * ml;
            float xv7 = xr[(th + 2) * 256 + w];
            float xv8 = xr[(th + 2) * 256 + wr] * mr;

            const float* wp = wb + (size_t)(c0 + ci) * 9;
            #pragma unroll
            for (int kci = 0; kci < 5; ++kci) {
                const float* wk = wp + (size_t)kci * (CC * 9);
                acc[kci] += wk[0] * xv0 + wk[1] * xv1 + wk[2] * xv2
                          + wk[3] * xv3 + wk[4] * xv4 + wk[5] * xv5
                          + wk[6] * xv6 + wk[7] * xv7 + wk[8] * xv8;
            }
        }
    }

    float* kb = kwsP + ((size_t)(cs * BB + b) * KK + kcg * 5) * (HH * WW)
                     + h * WW + w;
    #pragma unroll
    for (int kci = 0; kci < 5; ++kci)
        kb[(size_t)kci * (HH * WW)] = acc[kci];
}

// ---------------------------------------------------------------------------
// Kernel 2: fused softmax + local attention + (C->OUT) GEMM + 2x2-replicated
//           output write. 16-pixel blocks: grid 4*64*4 = 1024, 256 threads.
// ---------------------------------------------------------------------------
union FusedU {
    float xld[16 * 5 * 24];   // phase 2: x tile, 16 c x 5 rows x 20(+pad)
    float wch[16 * OUTC];     // phase 3: W2sT chunk
};

__global__ __launch_bounds__(256) void fused_kernel(
        const float* __restrict__ x,
        const float* __restrict__ w2st,
        const float* __restrict__ b1,
        const float* __restrict__ b2,
        const float* __restrict__ kwsP,
        float* __restrict__ out,
        int ncs) {
    __shared__ float pk[KK * 16];    // softmax probs       (1.6 KB)
    __shared__ float sK[CC * 16];    // attention out       (8 KB)
    __shared__ FusedU u;             //                     (8 KB)

    int bid = blockIdx.x;
    int wq = bid & 3;
    int h  = (bid >> 2) & 63;
    int b  = bid >> 8;
    int t  = threadIdx.x;

    // ---- Phase 1: sum ncs conv1 partials + bias -> logits ----
    for (int i = t; i < KK * 16; i += 256) {
        int kk = i >> 4, px = i & 15;
        float v = b1[kk];
        for (int cs = 0; cs < ncs; ++cs)
            v += kwsP[((size_t)(cs * BB + b) * KK + kk) * (HH * WW)
                      + h * WW + wq * 16 + px];
        pk[kk * 16 + px] = v;
    }
    __syncthreads();

    if (t < 16) {
        float mx = -1e30f;
        for (int k = 0; k < KK; ++k) mx = fmaxf(mx, pk[k * 16 + t]);
        float s = 0.f;
        for (int k = 0; k < KK; ++k) {
            float e = __expf(pk[k * 16 + t] - mx);
            pk[k * 16 + t] = e;
            s += e;
        }
        float inv = 1.f / s;
        for (int k = 0; k < KK; ++k) pk[k * 16 + t] *= inv;
    }
    __syncthreads();

    // ---- Phase 2: s[c][px] = sum_tap p[tap][px] * xpad[c][...] ----
    // thread = (px = t&15, clane = t>>4 in 0..15); c-chunks of 16.
    int px = t & 15, clane = t >> 4;
    float pr[KK];
    #pragma unroll
    for (int k = 0; k < KK; ++k) pr[k] = pk[k * 16 + px];

    const float* xb = x + (size_t)(b * CC) * (HH * WW);
    for (int ch = 0; ch < 8; ++ch) {
        __syncthreads();
        // stage 16 c x 5 rows x 20 cols (cols = wq*16-2 .. wq*16+17, zeroed OOB)
        for (int i = t; i < 1600; i += 256) {
            int c   = i / 100;
            int rem = i - c * 100;
            int di  = rem / 20;
            int col = rem - di * 20;
            int y  = h + di - 2;
            int xc = wq * 16 + col - 2;
            float v = 0.f;
            if (y >= 0 && y < HH && xc >= 0 && xc < WW)
                v = xb[(size_t)(ch * 16 + c) * (HH * WW) + y * WW + xc];
            u.xld[(c * 5 + di) * 24 + col] = v;
        }
        __syncthreads();

        float a = 0.f;
        const float* xr = &u.xld[clane * 120];
        #pragma unroll
        for (int di = 0; di < 5; ++di) {
            float xv[5];
            #pragma unroll
            for (int j = 0; j < 5; ++j) xv[j] = xr[di * 24 + px + j];
            #pragma unroll
            for (int dj = 0; dj < 5; ++dj) a += pr[di * 5 + dj] * xv[dj];
        }
        sK[(ch * 16 + clane) * 16 + px] = a;
    }

    // ---- Phase 3: V[o][px] = b2[o] + sum_c s[c][px] * W2sT[c][o] ----
    // thread = (slot = t&3 -> 4 px, og = t>>2 -> 2 outputs)
    int slot = t & 3, og = t >> 2;
    float2 bv = *(const float2*)(b2 + og * 2);
    float acc[8];
    acc[0] = bv.x; acc[1] = bv.x; acc[2] = bv.x; acc[3] = bv.x;
    acc[4] = bv.y; acc[5] = bv.y; acc[6] = bv.y; acc[7] = bv.y;

    for (int ch = 0; ch < 8; ++ch) {
        __syncthreads();
        for (int i = t; i < 16 * OUTC; i += 256)
            u.wch[i] = w2st[ch * 16 * OUTC + i];
        __syncthreads();
        #pragma unroll 4
        for (int cc = 0; cc < 16; ++cc) {
            float4 s4 = *(const float4*)&sK[(ch * 16 + cc) * 16 + slot * 4];
            float2 wv = *(const float2*)&u.wch[cc * OUTC + og * 2];
            acc[0] += wv.x * s4.x; acc[1] += wv.x * s4.y;
            acc[2] += wv.x * s4.z; acc[3] += wv.x * s4.w;
            acc[4] += wv.y * s4.x; acc[5] += wv.y * s4.y;
            acc[6] += wv.y * s4.z; acc[7] += wv.y * s4.w;
        }
    }

    // ---- write: 2x2-replicated, float4 pairs ----
    float* ob = out + (size_t)(b * OUTC) * (4 * HH * WW);
    int y0   = 2 * h;
    int colb = 2 * (wq * 16 + slot * 4);   // 8 consecutive floats
    #pragma unroll
    for (int oi = 0; oi < 2; ++oi) {
        int o = og * 2 + oi;
        float4 lo = make_float4(acc[oi*4+0], acc[oi*4+0], acc[oi*4+1], acc[oi*4+1]);
        float4 hi = make_float4(acc[oi*4+2], acc[oi*4+2], acc[oi*4+3], acc[oi*4+3]);
        float* r0 = ob + ((size_t)o * (2 * HH) + y0) * (2 * WW) + colb;
        *(float4*)(r0)              = lo;
        *(float4*)(r0 + 4)          = hi;
        *(float4*)(r0 + 2 * WW)     = lo;
        *(float4*)(r0 + 2 * WW + 4) = hi;
    }
}

// ---------------------------------------------------------------------------
extern "C" void kernel_launch(void* const* d_in, const int* in_sizes, int n_in,
                              void* d_out, int out_size, void* d_ws, size_t ws_size,
                              hipStream_t stream) {
    const float* x  = (const float*)d_in[0];
    const float* w1 = (const float*)d_in[1];
    const float* b1 = (const float*)d_in[2];
    const float* w2 = (const float*)d_in[3];
    const float* b2 = (const float*)d_in[4];
    float* out = (float*)d_out;

    const size_t slab = (size_t)BB * KK * HH * WW;   // 409600 floats per cs
    // pick largest c-split whose partials fit the workspace
    int ncs = 4;
    while (ncs > 1 &&
           (ncs * slab + (size_t)OUTC * CC) * sizeof(float) > ws_size)
        ncs >>= 1;

    float* kwsP = (float*)d_ws;
    float* w2st = kwsP + ncs * slab;

    prep_w2_kernel<<<64, 256, 0, stream>>>(w2, w2st);
    conv1_kernel<<<BB * 16 * ncs * 5, 256, 0, stream>>>(x, w1, kwsP, ncs, CC / ncs);
    fused_kernel<<<BB * HH * 4, 256, 0, stream>>>(x, w2st, b1, b2, kwsP, out, ncs);
}